// Round 18
// baseline (593.666 us; speedup 1.0000x reference)
//
#include <hip/hip_runtime.h>
#include <math.h>

#define N_NODES 10000
#define N_EDGES 40000

typedef __attribute__((ext_vector_type(8))) short bf16x8;
typedef __attribute__((ext_vector_type(4))) float f32x4;

__device__ inline unsigned short f2bf(float f) {
    unsigned u = __float_as_uint(f);
    return (unsigned short)((u + 0x7FFFu + ((u >> 16) & 1u)) >> 16);
}

__device__ inline float bf2f(unsigned short h) {
    return __uint_as_float((unsigned)h << 16);
}

__device__ inline bf16x8 pack8(const float* p) {
    f32x4 a0 = *(const f32x4*)p;
    f32x4 a1 = *(const f32x4*)(p + 4);
    bf16x8 r;
    r[0] = (short)f2bf(a0.x); r[1] = (short)f2bf(a0.y);
    r[2] = (short)f2bf(a0.z); r[3] = (short)f2bf(a0.w);
    r[4] = (short)f2bf(a1.x); r[5] = (short)f2bf(a1.y);
    r[6] = (short)f2bf(a1.z); r[7] = (short)f2bf(a1.w);
    return r;
}

// ---------------------------------------------------------------------------
// Tensor-product path tables. kind: 0=(0,0,0) 1=(0,1,1) 2=(1,0,1) 3=(1,1,0) 4=(1,1,1)
// ---------------------------------------------------------------------------
template <int L> struct PC;
template <> struct PC<0> {
    static constexpr int NP = 2;
    static constexpr int woff[3]  = {0, 1024, 1280};
    static constexpr int l2m3[2]  = {5, 3};
    static constexpr int inoff[2] = {0, 0};
    static constexpr int outoff[2]= {0, 32};
    static constexpr int kind[2]  = {0, 1};
    static constexpr float coef[2]= {0.17677670f, 0.17677670f};
};
template <> struct PC<1> {
    static constexpr int NP = 5;
    static constexpr int woff[6]  = {0, 1024, 1280, 1344, 1600, 1664};
    static constexpr int l2m3[5]  = {5, 3, 3, 5, 3};
    static constexpr int inoff[5] = {0, 0, 32, 32, 32};
    static constexpr int outoff[5]= {0, 32, 32, 0, 56};
    static constexpr int kind[5]  = {0, 1, 2, 3, 4};
    static constexpr float coef[5]= {0.15811388f, 0.15811388f, 0.15811388f, 0.09128709f, 0.25f};
};
template <> struct PC<2> {
    static constexpr int NP = 8;
    static constexpr int woff[9]  = {0, 1024, 1280, 1344, 1600, 1664, 1728, 1792, 2048};
    static constexpr int l2m3[8]  = {5, 3, 3, 5, 3, 3, 3, 5};
    static constexpr int inoff[8] = {0, 0, 32, 32, 32, 56, 56, 56};
    static constexpr int outoff[8]= {0, 32, 32, 0, 56, 56, 32, 80};
    static constexpr int kind[8]  = {0, 1, 2, 3, 4, 2, 4, 3};
    static constexpr float coef[8]= {0.15811388f, 0.14433757f, 0.14433757f, 0.09128709f,
                                     0.17677670f, 0.25f, 0.10206207f, 0.20412415f};
};
template <> struct PC<3> {
    static constexpr int NP = 10;
    static constexpr int woff[11] = {0, 1024, 1280, 1344, 1600, 1664, 1728, 1792, 2048, 3072, 3328};
    static constexpr int l2m3[10] = {5, 3, 3, 5, 3, 3, 3, 5, 5, 3};
    static constexpr int inoff[10]= {0, 0, 32, 32, 32, 56, 56, 56, 80, 80};
    static constexpr int outoff[10]={0, 32, 32, 0, 56, 56, 32, 80, 80, 56};
    static constexpr int kind[10] = {0, 1, 2, 3, 4, 2, 4, 3, 0, 1};
    static constexpr float coef[10]={0.15811388f, 0.14433757f, 0.14433757f, 0.09128709f,
                                     0.10206207f, 0.14433757f, 0.10206207f, 0.09128709f,
                                     0.15811388f, 0.14433757f};
};

// ---------------------------------------------------------------------------
// kpackf2: all 4 fc2 weight matrices -> bf16 B-fragment layout (one launch).
// ---------------------------------------------------------------------------
__global__ void kpackf2(const float* __restrict__ w0c, const float* __restrict__ w1c,
                        const float* __restrict__ w2c, const float* __restrict__ w3c,
                        unsigned short* __restrict__ dst)
{
    int idx = blockIdx.x * 256 + threadIdx.x;
    if (idx >= 99840) return;
    const float* w; int ncol; size_t doff; int rel;
    if (idx < 15360)      { w = w0c; ncol = 1280; doff = 0;      rel = idx; }
    else if (idx < 35328) { w = w1c; ncol = 1664; doff = 122880; rel = idx - 15360; }
    else if (idx < 59904) { w = w2c; ncol = 2048; doff = 282624; rel = idx - 35328; }
    else                  { w = w3c; ncol = 3328; doff = 479232; rel = idx - 59904; }
    int lane = rel & 63;
    int rest = rel >> 6;
    int t  = rest % 3;
    int jt = rest / 3;
    int n  = jt * 16 + (lane & 15);
    int k0 = 32 * t + 8 * (lane >> 4);
    bf16x8 v;
#pragma unroll
    for (int i = 0; i < 8; ++i) v[i] = (short)f2bf(w[(size_t)(k0 + i) * ncol + n]);
    *(bf16x8*)(dst + doff + (size_t)rel * 8) = v;
}

// kpackf1: all 4 fc1 matrices (ncol=96) in one launch.
__global__ void kpackf1(const float* __restrict__ w, unsigned short* __restrict__ dst)
{
    int idx = blockIdx.x * 256 + threadIdx.x;
    if (idx >= 4 * 1152) return;
    int L = idx / 1152, rel = idx % 1152;
    int lane = rel & 63;
    int rest = rel >> 6;
    int t  = rest % 3;
    int jt = rest / 3;
    int n  = jt * 16 + (lane & 15);
    int k0 = 32 * t + 8 * (lane >> 4);
    const float* wl = w + (size_t)L * 9216;
    bf16x8 v;
#pragma unroll
    for (int i = 0; i < 8; ++i) v[i] = (short)f2bf(wl[(size_t)(k0 + i) * 96 + n]);
    *(bf16x8*)(dst + (size_t)L * 9216 + (size_t)rel * 8) = v;
}

// ---------------------------------------------------------------------------
__global__ void ksemb(const float* __restrict__ sigma, float* __restrict__ semb)
{
    int n = blockIdx.x * 256 + threadIdx.x;
    if (n >= N_NODES) return;
    float t = logf(sigma[n] * (1.0f / 0.031415926535897934f)) * 2171.4724095f;
#pragma unroll
    for (int j = 0; j < 16; ++j) {
        float f = expf(-0.61402269f * (float)j);
        float a = t * f;
        semb[n * 32 + j]      = sinf(a);
        semb[n * 32 + 16 + j] = cosf(a);
    }
}

// ---------------------------------------------------------------------------
__global__ void knodemlp(const float* __restrict__ x, const float* __restrict__ semb,
                         const float* __restrict__ w1, const float* __restrict__ b1,
                         const float* __restrict__ w2, const float* __restrict__ b2,
                         float* __restrict__ na)
{
    __shared__ float xin[8][106];
    __shared__ float h1[8][32];
    int tid = threadIdx.x;
    int n0  = blockIdx.x * 8;
    for (int idx = tid; idx < 8 * 106; idx += 256) {
        int e = idx / 106, q = idx % 106;
        int n = n0 + e;
        float v = 0.f;
        if (n < N_NODES) v = (q < 74) ? x[n * 74 + q] : semb[n * 32 + (q - 74)];
        xin[e][q] = v;
    }
    __syncthreads();
    {
        int e = tid / 32, c = tid % 32;
        float s = b1[c];
        for (int f = 0; f < 106; ++f) s += xin[e][f] * w1[f * 32 + c];
        h1[e][c] = fmaxf(s, 0.f);
    }
    __syncthreads();
    {
        int e = tid / 32, c = tid % 32;
        int n = n0 + e;
        if (n < N_NODES) {
            float s = b2[c];
#pragma unroll
            for (int f = 0; f < 32; ++f) s += h1[e][f] * w2[f * 32 + c];
            na[n * 112 + c] = s;
        }
    }
}

// ---------------------------------------------------------------------------
__global__ void kedgepre(const float* __restrict__ pos, const float* __restrict__ eattr_in,
                         const float* __restrict__ semb, const int* __restrict__ ei,
                         const float* __restrict__ w1, const float* __restrict__ b1,
                         const float* __restrict__ w2, const float* __restrict__ b2,
                         float* __restrict__ sh, float* __restrict__ eemb, int* __restrict__ cnt)
{
    __shared__ float ea[8][86];
    __shared__ float h1[8][32];
    __shared__ float dl[8];
    __shared__ int   sl[8];
    int tid = threadIdx.x;
    int e0  = blockIdx.x * 8;
    if (tid < 8) {
        int ge = e0 + tid;
        int s = ei[ge], d = ei[N_EDGES + ge];
        sl[tid] = s;
        float dx = pos[d * 3 + 0] - pos[s * 3 + 0];
        float dy = pos[d * 3 + 1] - pos[s * 3 + 1];
        float dz = pos[d * 3 + 2] - pos[s * 3 + 2];
        float dist = sqrtf(dx * dx + dy * dy + dz * dz);
        dist = fmaxf(dist, 1e-6f);
        dl[tid] = dist;
        float inv = 1.7320508f / dist;
        sh[ge * 4 + 0] = 1.f;
        sh[ge * 4 + 1] = dx * inv;
        sh[ge * 4 + 2] = dy * inv;
        sh[ge * 4 + 3] = dz * inv;
        atomicAdd(&cnt[d], 1);
    }
    __syncthreads();
    for (int idx = tid; idx < 8 * 86; idx += 256) {
        int e = idx / 86, q = idx % 86;
        int ge = e0 + e;
        float v;
        if (q < 4)       v = eattr_in[ge * 4 + q];
        else if (q < 36) v = semb[sl[e] * 32 + (q - 4)];
        else {
            int qq = q - 36;
            float off = 5.f * (float)qq / 49.f;
            float dd  = dl[e] - off;
            v = expf(-48.02f * dd * dd);
        }
        ea[e][q] = v;
    }
    __syncthreads();
    {
        int e = tid / 32, c = tid % 32;
        float s = b1[c];
        for (int f = 0; f < 86; ++f) s += ea[e][f] * w1[f * 32 + c];
        h1[e][c] = fmaxf(s, 0.f);
    }
    __syncthreads();
    {
        int e = tid / 32, c = tid % 32;
        float s = b2[c];
#pragma unroll
        for (int f = 0; f < 32; ++f) s += h1[e][f] * w2[f * 32 + c];
        eemb[(e0 + e) * 32 + c] = s;
    }
}

// ---------------------------------------------------------------------------
// K3: fc1(MFMA) -> fc2(MFMA, 2-deep pipeline) -> TP epilogue, ZERO atomics.
// xs stored as bf16 (stride 120, 16B-aligned rows): LDS ~37.5KB -> 4 blk/CU.
// ---------------------------------------------------------------------------
template <int L>
__global__ __launch_bounds__(256, 2) void ktp(
    const float* __restrict__ na, const float* __restrict__ eemb,
    const float* __restrict__ sh, const int* __restrict__ ei,
    const unsigned short* __restrict__ w1pk, const float* __restrict__ fc1b,
    const unsigned short* __restrict__ wpk, const float* __restrict__ fc2b,
    float* __restrict__ out_tp)
{
    using C = PC<L>;
    constexpr int DIN  = (L == 0 ? 32 : L == 1 ? 56 : L == 2 ? 80 : 112);
    constexpr int DOUT = (L == 0 ? 56 : L == 1 ? 80 : 112);

    // uni: 2 oacc copies [2][32][113]; hbuf(32x100) overlays copy 0;
    // ys(32x36) overlays copy 1 (both dead before the oacc zeroing).
    alignas(16) __shared__ float uni[2 * 3616];
    alignas(16) __shared__ unsigned short xs[32 * 120];   // bf16, 16B-aligned rows
    __shared__ float shl4[128];
    __shared__ int   sdn[32], ddn[32];
    float* ys = &uni[3616];

    const int tid  = threadIdx.x;
    const int lane = tid & 63;
    const int wid  = tid >> 6;
    const int e0   = blockIdx.x * 32;
    const int m    = lane & 15;
    const int g    = lane >> 4;
    const int ehalf = wid >> 1;
    const int cpar  = wid & 1;

    if (tid < 32) { sdn[tid] = ei[e0 + tid]; ddn[tid] = ei[N_EDGES + e0 + tid]; }
    __syncthreads();

    for (int idx = tid; idx < 32 * DIN; idx += 256) {
        int e = idx / DIN, d = idx % DIN;
        xs[e * 120 + d] = f2bf(na[sdn[e] * 112 + d]);
    }
    for (int idx = tid; idx < 32 * 32; idx += 256) {
        int e = idx >> 5, d = idx & 31;
        ys[e * 36 + d] = na[ddn[e] * 112 + d];
    }
    if (tid < 128) shl4[tid] = sh[e0 * 4 + tid];
    __syncthreads();

    // fc1 A-fragments: xs row is already bf16 -> direct 16B load for src
    bf16x8 eaf[2][3];
#pragma unroll
    for (int mt = 0; mt < 2; ++mt) {
        int e = 16 * mt + m;
        eaf[mt][0] = pack8(&eemb[(size_t)(e0 + e) * 32 + 8 * g]);
        eaf[mt][1] = *(const bf16x8*)&xs[e * 120 + 8 * g];
        eaf[mt][2] = pack8(&ys[e * 36 + 8 * g]);
    }

    const bf16x8* w1p = (const bf16x8*)w1pk;
#pragma unroll
    for (int pass = 0; pass < 2; ++pass) {
        int jt = wid + 4 * pass;
        if (jt < 6) {
            bf16x8 fb0 = w1p[(jt * 3 + 0) * 64 + lane];
            bf16x8 fb1 = w1p[(jt * 3 + 1) * 64 + lane];
            bf16x8 fb2 = w1p[(jt * 3 + 2) * 64 + lane];
            float bias = fc1b[jt * 16 + m];
            f32x4 a0 = {bias, bias, bias, bias};
            f32x4 a1 = a0;
            a0 = __builtin_amdgcn_mfma_f32_16x16x32_bf16(eaf[0][0], fb0, a0, 0, 0, 0);
            a1 = __builtin_amdgcn_mfma_f32_16x16x32_bf16(eaf[1][0], fb0, a1, 0, 0, 0);
            a0 = __builtin_amdgcn_mfma_f32_16x16x32_bf16(eaf[0][1], fb1, a0, 0, 0, 0);
            a1 = __builtin_amdgcn_mfma_f32_16x16x32_bf16(eaf[1][1], fb1, a1, 0, 0, 0);
            a0 = __builtin_amdgcn_mfma_f32_16x16x32_bf16(eaf[0][2], fb2, a0, 0, 0, 0);
            a1 = __builtin_amdgcn_mfma_f32_16x16x32_bf16(eaf[1][2], fb2, a1, 0, 0, 0);
#pragma unroll
            for (int r = 0; r < 4; ++r) {
                uni[(0  + 4 * g + r) * 100 + jt * 16 + m] = fmaxf(a0[r], 0.f);
                uni[(16 + 4 * g + r) * 100 + jt * 16 + m] = fmaxf(a1[r], 0.f);
            }
        }
    }
    __syncthreads();

    // A fragments of h for THIS wave's 16 edges
    bf16x8 afrag[3];
#pragma unroll
    for (int t = 0; t < 3; ++t)
        afrag[t] = pack8(&uni[(16 * ehalf + m) * 100 + 32 * t + 8 * g]);

    float sy1[4], sy2[4], sy3[4];
#pragma unroll
    for (int r = 0; r < 4; ++r) {
        int e = 16 * ehalf + 4 * g + r;
        sy1[r] = shl4[e * 4 + 1];
        sy2[r] = shl4[e * 4 + 2];
        sy3[r] = shl4[e * 4 + 3];
    }
    __syncthreads();
    for (int idx = tid; idx < 2 * 3616; idx += 256) uni[idx] = 0.f;   // oacc2 := 0
    __syncthreads();

    const bf16x8* wp = (const bf16x8*)wpk;
    const int ebase = 16 * ehalf + 4 * g;
    const int lj    = m;
    float* oaccw = &uni[cpar * 3616];

#pragma clang loop unroll(disable)
    for (int p = 0; p < C::NP; ++p) {
        const int w0    = C::woff[p];
        const int iters = (C::woff[p + 1] - w0) / 32;   // tiles per parity (even, >=2)
        const int jtb   = w0 / 16 + cpar;
        const int sh3   = C::l2m3[p];
        const int mask  = (1 << sh3) - 1;
        const int w3i   = (16 * cpar + lj) & mask;
        const float cf  = C::coef[p];
        const int IN = C::inoff[p], OUT = C::outoff[p];
        const int knd = C::kind[p];

        float Ta[4], Tb[4], Tc[4];
#pragma unroll
        for (int s = 0; s < 4; ++s) { Ta[s] = 0.f; Tb[s] = 0.f; Tc[s] = 0.f; }

        auto epi = [&](f32x4 acc, int i2) {
            const int u = (i2 * 16 + lj) >> sh3;
            if (knd <= 1) {
#pragma unroll
                for (int r = 0; r < 4; ++r)
                    Ta[r] += bf2f(xs[(ebase + r) * 120 + IN + u]) * acc[r];
            } else if (knd == 2) {
#pragma unroll
                for (int r = 0; r < 4; ++r) {
                    const unsigned short* xe = &xs[(ebase + r) * 120 + IN + 3 * u];
                    Ta[r] += bf2f(xe[0]) * acc[r];
                    Tb[r] += bf2f(xe[1]) * acc[r];
                    Tc[r] += bf2f(xe[2]) * acc[r];
                }
            } else if (knd == 3) {
#pragma unroll
                for (int r = 0; r < 4; ++r) {
                    const unsigned short* xe = &xs[(ebase + r) * 120 + IN + 3 * u];
                    Ta[r] += (bf2f(xe[0]) * sy1[r] + bf2f(xe[1]) * sy2[r]
                            + bf2f(xe[2]) * sy3[r]) * acc[r];
                }
            } else {
#pragma unroll
                for (int r = 0; r < 4; ++r) {
                    const unsigned short* xe = &xs[(ebase + r) * 120 + IN + 3 * u];
                    float x0 = bf2f(xe[0]), x1 = bf2f(xe[1]), x2 = bf2f(xe[2]);
                    Ta[r] += (x1 * sy3[r] - x2 * sy2[r]) * acc[r];
                    Tb[r] += (x2 * sy1[r] - x0 * sy3[r]) * acc[r];
                    Tc[r] += (x0 * sy2[r] - x1 * sy1[r]) * acc[r];
                }
            }
        };

        // 2-deep software pipeline: stages A (even i) and B (odd i).
        int jtA = jtb;
        bf16x8 A0 = wp[(jtA * 3 + 0) * 64 + lane];
        bf16x8 A1 = wp[(jtA * 3 + 1) * 64 + lane];
        bf16x8 A2 = wp[(jtA * 3 + 2) * 64 + lane];
        float  Ab = fc2b[jtA * 16 + lj];
        int jtB = jtb + 2;
        bf16x8 B0 = wp[(jtB * 3 + 0) * 64 + lane];
        bf16x8 B1 = wp[(jtB * 3 + 1) * 64 + lane];
        bf16x8 B2 = wp[(jtB * 3 + 2) * 64 + lane];
        float  Bb = fc2b[jtB * 16 + lj];

#pragma clang loop unroll(disable)
        for (int i = 0; i < iters; i += 2) {
            f32x4 accA = {Ab, Ab, Ab, Ab};
            accA = __builtin_amdgcn_mfma_f32_16x16x32_bf16(afrag[0], A0, accA, 0, 0, 0);
            accA = __builtin_amdgcn_mfma_f32_16x16x32_bf16(afrag[1], A1, accA, 0, 0, 0);
            accA = __builtin_amdgcn_mfma_f32_16x16x32_bf16(afrag[2], A2, accA, 0, 0, 0);
            if (i + 2 < iters) {
                int jtn = jtb + 2 * (i + 2);
                A0 = wp[(jtn * 3 + 0) * 64 + lane];
                A1 = wp[(jtn * 3 + 1) * 64 + lane];
                A2 = wp[(jtn * 3 + 2) * 64 + lane];
                Ab = fc2b[jtn * 16 + lj];
            }
            epi(accA, 2 * i + cpar);

            f32x4 accB = {Bb, Bb, Bb, Bb};
            accB = __builtin_amdgcn_mfma_f32_16x16x32_bf16(afrag[0], B0, accB, 0, 0, 0);
            accB = __builtin_amdgcn_mfma_f32_16x16x32_bf16(afrag[1], B1, accB, 0, 0, 0);
            accB = __builtin_amdgcn_mfma_f32_16x16x32_bf16(afrag[2], B2, accB, 0, 0, 0);
            if (i + 3 < iters) {
                int jtn = jtb + 2 * (i + 3);
                B0 = wp[(jtn * 3 + 0) * 64 + lane];
                B1 = wp[(jtn * 3 + 1) * 64 + lane];
                B2 = wp[(jtn * 3 + 2) * 64 + lane];
                Bb = fc2b[jtn * 16 + lj];
            }
            epi(accB, 2 * (i + 1) + cpar);
        }

        // within-wave alias (lj, lj+8) for mask==7 paths -> shfl combine
        const bool halfred = (mask == 7);
        if (halfred) {
#pragma unroll
            for (int s = 0; s < 4; ++s) {
                Ta[s] += __shfl_xor(Ta[s], 8);
                if (knd == 2 || knd == 4) {
                    Tb[s] += __shfl_xor(Tb[s], 8);
                    Tc[s] += __shfl_xor(Tc[s], 8);
                }
            }
        }
        if (!halfred || (lj & 8) == 0) {
#pragma unroll
            for (int r = 0; r < 4; ++r) {
                const int e = ebase + r;
                float* oa = &oaccw[e * 113 + OUT];
                if (knd == 0 || knd == 3) {
                    oa[w3i] += cf * Ta[r];
                } else if (knd == 1) {
                    oa[3 * w3i + 0] += cf * Ta[r] * sy1[r];
                    oa[3 * w3i + 1] += cf * Ta[r] * sy2[r];
                    oa[3 * w3i + 2] += cf * Ta[r] * sy3[r];
                } else {
                    oa[3 * w3i + 0] += cf * Ta[r];
                    oa[3 * w3i + 1] += cf * Tb[r];
                    oa[3 * w3i + 2] += cf * Tc[r];
                }
            }
        }
    }
    __syncthreads();

    // scatter: sum the 2 parity copies, one global atomic per (e,d)
    for (int idx = tid; idx < 32 * DOUT; idx += 256) {
        int e = idx / DOUT, d = idx % DOUT;
        float s = uni[e * 113 + d] + uni[3616 + e * 113 + d];
        unsafeAtomicAdd(&out_tp[ddn[e] * 112 + d], s);
    }
}

// ---------------------------------------------------------------------------
// knodestats: outb = tp/cnt + pad(na); per-dim sum/sumsq -> atomic into sbuf.
// grid 320 x 512: full-chip streaming (was 40 blocks = 16% of CUs).
// ---------------------------------------------------------------------------
__global__ void knodestats(const float* __restrict__ tp, const int* __restrict__ cnt,
                           const float* __restrict__ na, float* __restrict__ outb,
                           float* __restrict__ sbuf, int din, int dout)
{
    int t = threadIdx.x;
    if (t >= 448) return;
    int d = t % 112;
    int q = t / 112;
    if (d >= dout) return;
    float s = 0.f, s2 = 0.f;
    for (int n = blockIdx.x * 4 + q; n < N_NODES; n += 1280) {
        float c = fmaxf((float)cnt[n], 1.f);
        float v = tp[n * 112 + d] / c + (d < din ? na[n * 112 + d] : 0.f);
        outb[n * 112 + d] = v;
        s += v; s2 += v * v;
    }
    atomicAdd(&sbuf[d], s);
    atomicAdd(&sbuf[256 + d], s2);
}

// ---------------------------------------------------------------------------
// kapplyfuse: recompute scale/bias from sbuf per block, apply normalization,
// zero tp + the ENTIRE next sbuf (both halves).
// ---------------------------------------------------------------------------
__global__ void kapplyfuse(const float* __restrict__ outb, const float* __restrict__ sbuf,
                           float* __restrict__ dst, float* __restrict__ tpz,
                           float* __restrict__ nextsbuf, int dout, int vend)
{
    __shared__ float sc[112], bs[112];
    int tid = threadIdx.x;
    if (tid < dout) {
        const float invN = 1.f / (float)N_NODES;
        float scv, bsv;
        if (tid < 32 || tid >= vend) {
            float mn  = sbuf[tid] * invN;
            float var = sbuf[256 + tid] * invN - mn * mn;
            scv = rsqrtf(var + 1e-5f); bsv = mn;
        } else {
            int b = 32 + ((tid - 32) / 3) * 3;
            float n2 = (sbuf[256 + b] + sbuf[256 + b + 1] + sbuf[256 + b + 2]) * (invN / 3.f);
            scv = rsqrtf(n2 + 1e-5f); bsv = 0.f;
        }
        sc[tid] = scv; bs[tid] = bsv;
    }
    __syncthreads();
    int idx = blockIdx.x * 256 + tid;
    if (idx < N_NODES * dout) {
        int n = idx / dout, d = idx % dout;
        dst[n * 112 + d] = (outb[n * 112 + d] - bs[d]) * sc[d];
    }
    if (tpz) {
        for (int z = idx; z < N_NODES * 112; z += gridDim.x * 256) tpz[z] = 0.f;
        if (blockIdx.x == 0) { nextsbuf[tid] = 0.f; nextsbuf[256 + tid] = 0.f; }
    }
}

// ---------------------------------------------------------------------------
extern "C" void kernel_launch(void* const* d_in, const int* in_sizes, int n_in,
                              void* d_out, int out_size, void* d_ws, size_t ws_size,
                              hipStream_t stream)
{
    (void)in_sizes; (void)n_in; (void)out_size; (void)ws_size;
    const float* x     = (const float*)d_in[0];
    const float* pos   = (const float*)d_in[1];
    const float* sigma = (const float*)d_in[2];
    const float* eain  = (const float*)d_in[3];
    const float* nw1 = (const float*)d_in[4];  const float* nb1 = (const float*)d_in[5];
    const float* nw2 = (const float*)d_in[6];  const float* nb2 = (const float*)d_in[7];
    const float* ew1 = (const float*)d_in[8];  const float* eb1 = (const float*)d_in[9];
    const float* ew2 = (const float*)d_in[10]; const float* eb2 = (const float*)d_in[11];
    const float* fc1w = (const float*)d_in[12];
    const float* fc1b = (const float*)d_in[13];
    const float* fc2w[4] = {(const float*)d_in[14], (const float*)d_in[16],
                            (const float*)d_in[18], (const float*)d_in[20]};
    const float* fc2b[4] = {(const float*)d_in[15], (const float*)d_in[17],
                            (const float*)d_in[19], (const float*)d_in[21]};
    const int* ei = (const int*)d_in[22];

    float* ws   = (float*)d_ws;
    float* semb = ws + 0;            // N*32
    float* na   = ws + 320000;       // N*112
    float* outb = ws + 1440000;      // N*112
    float* tp   = ws + 2560000;      // N*112
    float* sh   = ws + 3680000;      // E*4
    float* eemb = ws + 3840000;      // E*32
    int*   cnt  = (int*)(ws + 5120000); // N
    float* sbufA = ws + 5130000;     // 512 (sums | sumsq)
    float* sbufB = ws + 5130512;     // 512
    unsigned short* wpk  = (unsigned short*)(ws + 5131264);  // fc2 packed: 798720 bf16
    unsigned short* w1pk = wpk + 798720;                      // fc1 packed: 36864 bf16
    float* out = (float*)d_out;

    const size_t WOFF_[4] = {0, 122880, 282624, 479232};

    hipMemsetAsync(cnt, 0, N_NODES * sizeof(int), stream);
    hipMemsetAsync(tp, 0, (size_t)N_NODES * 112 * sizeof(float), stream);
    hipMemsetAsync(sbufA, 0, 1024 * sizeof(float), stream);
    kpackf2<<<(99840 + 255) / 256, 256, 0, stream>>>(fc2w[0], fc2w[1], fc2w[2], fc2w[3], wpk);
    kpackf1<<<(4608 + 255) / 256, 256, 0, stream>>>(fc1w, w1pk);
    ksemb<<<(N_NODES + 255) / 256, 256, 0, stream>>>(sigma, semb);
    knodemlp<<<N_NODES / 8, 256, 0, stream>>>(x, semb, nw1, nb1, nw2, nb2, na);
    kedgepre<<<N_EDGES / 8, 256, 0, stream>>>(pos, eain, semb, ei, ew1, eb1, ew2, eb2,
                                              sh, eemb, cnt);

    const int DIN_[4]  = {32, 56, 80, 112};
    const int DOUT_[4] = {56, 80, 112, 112};
    const int VEND_[4] = {56, 80, 80, 80};
    for (int L = 0; L < 4; ++L) {
        float* sbuf  = (L & 1) ? sbufB : sbufA;
        float* nsbuf = (L & 1) ? sbufA : sbufB;
        switch (L) {
        case 0: ktp<0><<<N_EDGES / 32, 256, 0, stream>>>(na, eemb, sh, ei,
                    w1pk + 0 * 9216, fc1b + 0 * 96, wpk + WOFF_[0], fc2b[0], tp); break;
        case 1: ktp<1><<<N_EDGES / 32, 256, 0, stream>>>(na, eemb, sh, ei,
                    w1pk + 1 * 9216, fc1b + 1 * 96, wpk + WOFF_[1], fc2b[1], tp); break;
        case 2: ktp<2><<<N_EDGES / 32, 256, 0, stream>>>(na, eemb, sh, ei,
                    w1pk + 2 * 9216, fc1b + 2 * 96, wpk + WOFF_[2], fc2b[2], tp); break;
        default: ktp<3><<<N_EDGES / 32, 256, 0, stream>>>(na, eemb, sh, ei,
                    w1pk + 3 * 9216, fc1b + 3 * 96, wpk + WOFF_[3], fc2b[3], tp); break;
        }
        knodestats<<<320, 512, 0, stream>>>(tp, cnt, na, outb, sbuf, DIN_[L], DOUT_[L]);
        float* dstp = (L == 3) ? out : na;
        float* tpz  = (L == 3) ? nullptr : tp;
        kapplyfuse<<<(N_NODES * DOUT_[L] + 255) / 256, 256, 0, stream>>>(
            outb, sbuf, dstp, tpz, nsbuf, DOUT_[L], VEND_[L]);
    }
}

// Round 19
// 499.421 us; speedup vs baseline: 1.1887x; 1.1887x over previous
//
#include <hip/hip_runtime.h>
#include <math.h>

#define N_NODES 10000
#define N_EDGES 40000

typedef __attribute__((ext_vector_type(8))) short bf16x8;
typedef __attribute__((ext_vector_type(4))) float f32x4;

__device__ inline unsigned short f2bf(float f) {
    unsigned u = __float_as_uint(f);
    return (unsigned short)((u + 0x7FFFu + ((u >> 16) & 1u)) >> 16);
}

__device__ inline bf16x8 pack8(const float* p) {
    f32x4 a0 = *(const f32x4*)p;
    f32x4 a1 = *(const f32x4*)(p + 4);
    bf16x8 r;
    r[0] = (short)f2bf(a0.x); r[1] = (short)f2bf(a0.y);
    r[2] = (short)f2bf(a0.z); r[3] = (short)f2bf(a0.w);
    r[4] = (short)f2bf(a1.x); r[5] = (short)f2bf(a1.y);
    r[6] = (short)f2bf(a1.z); r[7] = (short)f2bf(a1.w);
    return r;
}

// ---------------------------------------------------------------------------
// Tensor-product path tables. kind: 0=(0,0,0) 1=(0,1,1) 2=(1,0,1) 3=(1,1,0) 4=(1,1,1)
// ---------------------------------------------------------------------------
template <int L> struct PC;
template <> struct PC<0> {
    static constexpr int NP = 2;
    static constexpr int woff[3]  = {0, 1024, 1280};
    static constexpr int l2m3[2]  = {5, 3};
    static constexpr int inoff[2] = {0, 0};
    static constexpr int outoff[2]= {0, 32};
    static constexpr int kind[2]  = {0, 1};
    static constexpr float coef[2]= {0.17677670f, 0.17677670f};
};
template <> struct PC<1> {
    static constexpr int NP = 5;
    static constexpr int woff[6]  = {0, 1024, 1280, 1344, 1600, 1664};
    static constexpr int l2m3[5]  = {5, 3, 3, 5, 3};
    static constexpr int inoff[5] = {0, 0, 32, 32, 32};
    static constexpr int outoff[5]= {0, 32, 32, 0, 56};
    static constexpr int kind[5]  = {0, 1, 2, 3, 4};
    static constexpr float coef[5]= {0.15811388f, 0.15811388f, 0.15811388f, 0.09128709f, 0.25f};
};
template <> struct PC<2> {
    static constexpr int NP = 8;
    static constexpr int woff[9]  = {0, 1024, 1280, 1344, 1600, 1664, 1728, 1792, 2048};
    static constexpr int l2m3[8]  = {5, 3, 3, 5, 3, 3, 3, 5};
    static constexpr int inoff[8] = {0, 0, 32, 32, 32, 56, 56, 56};
    static constexpr int outoff[8]= {0, 32, 32, 0, 56, 56, 32, 80};
    static constexpr int kind[8]  = {0, 1, 2, 3, 4, 2, 4, 3};
    static constexpr float coef[8]= {0.15811388f, 0.14433757f, 0.14433757f, 0.09128709f,
                                     0.17677670f, 0.25f, 0.10206207f, 0.20412415f};
};
template <> struct PC<3> {
    static constexpr int NP = 10;
    static constexpr int woff[11] = {0, 1024, 1280, 1344, 1600, 1664, 1728, 1792, 2048, 3072, 3328};
    static constexpr int l2m3[10] = {5, 3, 3, 5, 3, 3, 3, 5, 5, 3};
    static constexpr int inoff[10]= {0, 0, 32, 32, 32, 56, 56, 56, 80, 80};
    static constexpr int outoff[10]={0, 32, 32, 0, 56, 56, 32, 80, 80, 56};
    static constexpr int kind[10] = {0, 1, 2, 3, 4, 2, 4, 3, 0, 1};
    static constexpr float coef[10]={0.15811388f, 0.14433757f, 0.14433757f, 0.09128709f,
                                     0.10206207f, 0.14433757f, 0.10206207f, 0.09128709f,
                                     0.15811388f, 0.14433757f};
};

// ---------------------------------------------------------------------------
// kpackf2: all 4 fc2 weight matrices -> bf16 B-fragment layout (one launch).
// ---------------------------------------------------------------------------
__global__ void kpackf2(const float* __restrict__ w0c, const float* __restrict__ w1c,
                        const float* __restrict__ w2c, const float* __restrict__ w3c,
                        unsigned short* __restrict__ dst)
{
    int idx = blockIdx.x * 256 + threadIdx.x;
    if (idx >= 99840) return;
    const float* w; int ncol; size_t doff; int rel;
    if (idx < 15360)      { w = w0c; ncol = 1280; doff = 0;      rel = idx; }
    else if (idx < 35328) { w = w1c; ncol = 1664; doff = 122880; rel = idx - 15360; }
    else if (idx < 59904) { w = w2c; ncol = 2048; doff = 282624; rel = idx - 35328; }
    else                  { w = w3c; ncol = 3328; doff = 479232; rel = idx - 59904; }
    int lane = rel & 63;
    int rest = rel >> 6;
    int t  = rest % 3;
    int jt = rest / 3;
    int n  = jt * 16 + (lane & 15);
    int k0 = 32 * t + 8 * (lane >> 4);
    bf16x8 v;
#pragma unroll
    for (int i = 0; i < 8; ++i) v[i] = (short)f2bf(w[(size_t)(k0 + i) * ncol + n]);
    *(bf16x8*)(dst + doff + (size_t)rel * 8) = v;
}

// kpackf1: all 4 fc1 matrices (ncol=96) in one launch.
__global__ void kpackf1(const float* __restrict__ w, unsigned short* __restrict__ dst)
{
    int idx = blockIdx.x * 256 + threadIdx.x;
    if (idx >= 4 * 1152) return;
    int L = idx / 1152, rel = idx % 1152;
    int lane = rel & 63;
    int rest = rel >> 6;
    int t  = rest % 3;
    int jt = rest / 3;
    int n  = jt * 16 + (lane & 15);
    int k0 = 32 * t + 8 * (lane >> 4);
    const float* wl = w + (size_t)L * 9216;
    bf16x8 v;
#pragma unroll
    for (int i = 0; i < 8; ++i) v[i] = (short)f2bf(wl[(size_t)(k0 + i) * 96 + n]);
    *(bf16x8*)(dst + (size_t)L * 9216 + (size_t)rel * 8) = v;
}

// ---------------------------------------------------------------------------
__global__ void ksemb(const float* __restrict__ sigma, float* __restrict__ semb)
{
    int n = blockIdx.x * 256 + threadIdx.x;
    if (n >= N_NODES) return;
    float t = logf(sigma[n] * (1.0f / 0.031415926535897934f)) * 2171.4724095f;
#pragma unroll
    for (int j = 0; j < 16; ++j) {
        float f = expf(-0.61402269f * (float)j);
        float a = t * f;
        semb[n * 32 + j]      = sinf(a);
        semb[n * 32 + 16 + j] = cosf(a);
    }
}

// ---------------------------------------------------------------------------
__global__ void knodemlp(const float* __restrict__ x, const float* __restrict__ semb,
                         const float* __restrict__ w1, const float* __restrict__ b1,
                         const float* __restrict__ w2, const float* __restrict__ b2,
                         float* __restrict__ na)
{
    __shared__ float xin[8][106];
    __shared__ float h1[8][32];
    int tid = threadIdx.x;
    int n0  = blockIdx.x * 8;
    for (int idx = tid; idx < 8 * 106; idx += 256) {
        int e = idx / 106, q = idx % 106;
        int n = n0 + e;
        float v = 0.f;
        if (n < N_NODES) v = (q < 74) ? x[n * 74 + q] : semb[n * 32 + (q - 74)];
        xin[e][q] = v;
    }
    __syncthreads();
    {
        int e = tid / 32, c = tid % 32;
        float s = b1[c];
        for (int f = 0; f < 106; ++f) s += xin[e][f] * w1[f * 32 + c];
        h1[e][c] = fmaxf(s, 0.f);
    }
    __syncthreads();
    {
        int e = tid / 32, c = tid % 32;
        int n = n0 + e;
        if (n < N_NODES) {
            float s = b2[c];
#pragma unroll
            for (int f = 0; f < 32; ++f) s += h1[e][f] * w2[f * 32 + c];
            na[n * 112 + c] = s;
        }
    }
}

// ---------------------------------------------------------------------------
__global__ void kedgepre(const float* __restrict__ pos, const float* __restrict__ eattr_in,
                         const float* __restrict__ semb, const int* __restrict__ ei,
                         const float* __restrict__ w1, const float* __restrict__ b1,
                         const float* __restrict__ w2, const float* __restrict__ b2,
                         float* __restrict__ sh, float* __restrict__ eemb, int* __restrict__ cnt)
{
    __shared__ float ea[8][86];
    __shared__ float h1[8][32];
    __shared__ float dl[8];
    __shared__ int   sl[8];
    int tid = threadIdx.x;
    int e0  = blockIdx.x * 8;
    if (tid < 8) {
        int ge = e0 + tid;
        int s = ei[ge], d = ei[N_EDGES + ge];
        sl[tid] = s;
        float dx = pos[d * 3 + 0] - pos[s * 3 + 0];
        float dy = pos[d * 3 + 1] - pos[s * 3 + 1];
        float dz = pos[d * 3 + 2] - pos[s * 3 + 2];
        float dist = sqrtf(dx * dx + dy * dy + dz * dz);
        dist = fmaxf(dist, 1e-6f);
        dl[tid] = dist;
        float inv = 1.7320508f / dist;
        sh[ge * 4 + 0] = 1.f;
        sh[ge * 4 + 1] = dx * inv;
        sh[ge * 4 + 2] = dy * inv;
        sh[ge * 4 + 3] = dz * inv;
        atomicAdd(&cnt[d], 1);
    }
    __syncthreads();
    for (int idx = tid; idx < 8 * 86; idx += 256) {
        int e = idx / 86, q = idx % 86;
        int ge = e0 + e;
        float v;
        if (q < 4)       v = eattr_in[ge * 4 + q];
        else if (q < 36) v = semb[sl[e] * 32 + (q - 4)];
        else {
            int qq = q - 36;
            float off = 5.f * (float)qq / 49.f;
            float dd  = dl[e] - off;
            v = expf(-48.02f * dd * dd);
        }
        ea[e][q] = v;
    }
    __syncthreads();
    {
        int e = tid / 32, c = tid % 32;
        float s = b1[c];
        for (int f = 0; f < 86; ++f) s += ea[e][f] * w1[f * 32 + c];
        h1[e][c] = fmaxf(s, 0.f);
    }
    __syncthreads();
    {
        int e = tid / 32, c = tid % 32;
        float s = b2[c];
#pragma unroll
        for (int f = 0; f < 32; ++f) s += h1[e][f] * w2[f * 32 + c];
        eemb[(e0 + e) * 32 + c] = s;
    }
}

// ---------------------------------------------------------------------------
// K3 (R17-verbatim): fc1(MFMA) -> fc2(MFMA, 2-deep pipeline) -> TP epilogue,
// ZERO atomics. f32 xs; ys overlays uni copy-1. LDS ~44.2KB.
// ---------------------------------------------------------------------------
template <int L>
__global__ __launch_bounds__(256, 2) void ktp(
    const float* __restrict__ na, const float* __restrict__ eemb,
    const float* __restrict__ sh, const int* __restrict__ ei,
    const unsigned short* __restrict__ w1pk, const float* __restrict__ fc1b,
    const unsigned short* __restrict__ wpk, const float* __restrict__ fc2b,
    float* __restrict__ out_tp)
{
    using C = PC<L>;
    constexpr int DIN  = (L == 0 ? 32 : L == 1 ? 56 : L == 2 ? 80 : 112);
    constexpr int DOUT = (L == 0 ? 56 : L == 1 ? 80 : 112);

    alignas(16) __shared__ float uni[2 * 3616];
    alignas(16) __shared__ float xs[3616];
    __shared__ float shl4[128];
    __shared__ int   sdn[32], ddn[32];
    float* ys = &uni[3616];

    const int tid  = threadIdx.x;
    const int lane = tid & 63;
    const int wid  = tid >> 6;
    const int e0   = blockIdx.x * 32;
    const int m    = lane & 15;
    const int g    = lane >> 4;
    const int ehalf = wid >> 1;
    const int cpar  = wid & 1;

    if (tid < 32) { sdn[tid] = ei[e0 + tid]; ddn[tid] = ei[N_EDGES + e0 + tid]; }
    __syncthreads();

    for (int idx = tid; idx < 32 * DIN; idx += 256) {
        int e = idx / DIN, d = idx % DIN;
        xs[e * 113 + d] = na[sdn[e] * 112 + d];
    }
    for (int idx = tid; idx < 32 * 32; idx += 256) {
        int e = idx >> 5, d = idx & 31;
        ys[e * 36 + d] = na[ddn[e] * 112 + d];
    }
    if (tid < 128) shl4[tid] = sh[e0 * 4 + tid];
    __syncthreads();

    bf16x8 eaf[2][3];
#pragma unroll
    for (int mt = 0; mt < 2; ++mt) {
        int e = 16 * mt + m;
        eaf[mt][0] = pack8(&eemb[(size_t)(e0 + e) * 32 + 8 * g]);
        eaf[mt][1] = pack8(&xs[e * 113 + 8 * g]);
        eaf[mt][2] = pack8(&ys[e * 36 + 8 * g]);
    }

    const bf16x8* w1p = (const bf16x8*)w1pk;
#pragma unroll
    for (int pass = 0; pass < 2; ++pass) {
        int jt = wid + 4 * pass;
        if (jt < 6) {
            bf16x8 fb0 = w1p[(jt * 3 + 0) * 64 + lane];
            bf16x8 fb1 = w1p[(jt * 3 + 1) * 64 + lane];
            bf16x8 fb2 = w1p[(jt * 3 + 2) * 64 + lane];
            float bias = fc1b[jt * 16 + m];
            f32x4 a0 = {bias, bias, bias, bias};
            f32x4 a1 = a0;
            a0 = __builtin_amdgcn_mfma_f32_16x16x32_bf16(eaf[0][0], fb0, a0, 0, 0, 0);
            a1 = __builtin_amdgcn_mfma_f32_16x16x32_bf16(eaf[1][0], fb0, a1, 0, 0, 0);
            a0 = __builtin_amdgcn_mfma_f32_16x16x32_bf16(eaf[0][1], fb1, a0, 0, 0, 0);
            a1 = __builtin_amdgcn_mfma_f32_16x16x32_bf16(eaf[1][1], fb1, a1, 0, 0, 0);
            a0 = __builtin_amdgcn_mfma_f32_16x16x32_bf16(eaf[0][2], fb2, a0, 0, 0, 0);
            a1 = __builtin_amdgcn_mfma_f32_16x16x32_bf16(eaf[1][2], fb2, a1, 0, 0, 0);
#pragma unroll
            for (int r = 0; r < 4; ++r) {
                uni[(0  + 4 * g + r) * 100 + jt * 16 + m] = fmaxf(a0[r], 0.f);
                uni[(16 + 4 * g + r) * 100 + jt * 16 + m] = fmaxf(a1[r], 0.f);
            }
        }
    }
    __syncthreads();

    bf16x8 afrag[3];
#pragma unroll
    for (int t = 0; t < 3; ++t)
        afrag[t] = pack8(&uni[(16 * ehalf + m) * 100 + 32 * t + 8 * g]);

    float sy1[4], sy2[4], sy3[4];
#pragma unroll
    for (int r = 0; r < 4; ++r) {
        int e = 16 * ehalf + 4 * g + r;
        sy1[r] = shl4[e * 4 + 1];
        sy2[r] = shl4[e * 4 + 2];
        sy3[r] = shl4[e * 4 + 3];
    }
    __syncthreads();
    for (int idx = tid; idx < 2 * 3616; idx += 256) uni[idx] = 0.f;   // oacc2 := 0
    __syncthreads();

    const bf16x8* wp = (const bf16x8*)wpk;
    const int ebase = 16 * ehalf + 4 * g;
    const int lj    = m;
    float* oaccw = &uni[cpar * 3616];

#pragma clang loop unroll(disable)
    for (int p = 0; p < C::NP; ++p) {
        const int w0    = C::woff[p];
        const int iters = (C::woff[p + 1] - w0) / 32;   // tiles per parity (even, >=2)
        const int jtb   = w0 / 16 + cpar;
        const int sh3   = C::l2m3[p];
        const int mask  = (1 << sh3) - 1;
        const int w3i   = (16 * cpar + lj) & mask;
        const float cf  = C::coef[p];
        const int IN = C::inoff[p], OUT = C::outoff[p];
        const int knd = C::kind[p];

        float Ta[4], Tb[4], Tc[4];
#pragma unroll
        for (int s = 0; s < 4; ++s) { Ta[s] = 0.f; Tb[s] = 0.f; Tc[s] = 0.f; }

        auto epi = [&](f32x4 acc, int i2) {
            const int u = (i2 * 16 + lj) >> sh3;
            if (knd <= 1) {
#pragma unroll
                for (int r = 0; r < 4; ++r)
                    Ta[r] += xs[(ebase + r) * 113 + IN + u] * acc[r];
            } else if (knd == 2) {
#pragma unroll
                for (int r = 0; r < 4; ++r) {
                    const float* xe = &xs[(ebase + r) * 113 + IN + 3 * u];
                    Ta[r] += xe[0] * acc[r];
                    Tb[r] += xe[1] * acc[r];
                    Tc[r] += xe[2] * acc[r];
                }
            } else if (knd == 3) {
#pragma unroll
                for (int r = 0; r < 4; ++r) {
                    const float* xe = &xs[(ebase + r) * 113 + IN + 3 * u];
                    Ta[r] += (xe[0] * sy1[r] + xe[1] * sy2[r] + xe[2] * sy3[r]) * acc[r];
                }
            } else {
#pragma unroll
                for (int r = 0; r < 4; ++r) {
                    const float* xe = &xs[(ebase + r) * 113 + IN + 3 * u];
                    Ta[r] += (xe[1] * sy3[r] - xe[2] * sy2[r]) * acc[r];
                    Tb[r] += (xe[2] * sy1[r] - xe[0] * sy3[r]) * acc[r];
                    Tc[r] += (xe[0] * sy2[r] - xe[1] * sy1[r]) * acc[r];
                }
            }
        };

        // 2-deep software pipeline: stages A (even i) and B (odd i).
        int jtA = jtb;
        bf16x8 A0 = wp[(jtA * 3 + 0) * 64 + lane];
        bf16x8 A1 = wp[(jtA * 3 + 1) * 64 + lane];
        bf16x8 A2 = wp[(jtA * 3 + 2) * 64 + lane];
        float  Ab = fc2b[jtA * 16 + lj];
        int jtB = jtb + 2;
        bf16x8 B0 = wp[(jtB * 3 + 0) * 64 + lane];
        bf16x8 B1 = wp[(jtB * 3 + 1) * 64 + lane];
        bf16x8 B2 = wp[(jtB * 3 + 2) * 64 + lane];
        float  Bb = fc2b[jtB * 16 + lj];

#pragma clang loop unroll(disable)
        for (int i = 0; i < iters; i += 2) {
            f32x4 accA = {Ab, Ab, Ab, Ab};
            accA = __builtin_amdgcn_mfma_f32_16x16x32_bf16(afrag[0], A0, accA, 0, 0, 0);
            accA = __builtin_amdgcn_mfma_f32_16x16x32_bf16(afrag[1], A1, accA, 0, 0, 0);
            accA = __builtin_amdgcn_mfma_f32_16x16x32_bf16(afrag[2], A2, accA, 0, 0, 0);
            if (i + 2 < iters) {
                int jtn = jtb + 2 * (i + 2);
                A0 = wp[(jtn * 3 + 0) * 64 + lane];
                A1 = wp[(jtn * 3 + 1) * 64 + lane];
                A2 = wp[(jtn * 3 + 2) * 64 + lane];
                Ab = fc2b[jtn * 16 + lj];
            }
            epi(accA, 2 * i + cpar);

            f32x4 accB = {Bb, Bb, Bb, Bb};
            accB = __builtin_amdgcn_mfma_f32_16x16x32_bf16(afrag[0], B0, accB, 0, 0, 0);
            accB = __builtin_amdgcn_mfma_f32_16x16x32_bf16(afrag[1], B1, accB, 0, 0, 0);
            accB = __builtin_amdgcn_mfma_f32_16x16x32_bf16(afrag[2], B2, accB, 0, 0, 0);
            if (i + 3 < iters) {
                int jtn = jtb + 2 * (i + 3);
                B0 = wp[(jtn * 3 + 0) * 64 + lane];
                B1 = wp[(jtn * 3 + 1) * 64 + lane];
                B2 = wp[(jtn * 3 + 2) * 64 + lane];
                Bb = fc2b[jtn * 16 + lj];
            }
            epi(accB, 2 * (i + 1) + cpar);
        }

        // within-wave alias (lj, lj+8) for mask==7 paths -> shfl combine
        const bool halfred = (mask == 7);
        if (halfred) {
#pragma unroll
            for (int s = 0; s < 4; ++s) {
                Ta[s] += __shfl_xor(Ta[s], 8);
                if (knd == 2 || knd == 4) {
                    Tb[s] += __shfl_xor(Tb[s], 8);
                    Tc[s] += __shfl_xor(Tc[s], 8);
                }
            }
        }
        if (!halfred || (lj & 8) == 0) {
#pragma unroll
            for (int r = 0; r < 4; ++r) {
                const int e = ebase + r;
                float* oa = &oaccw[e * 113 + OUT];
                if (knd == 0 || knd == 3) {
                    oa[w3i] += cf * Ta[r];
                } else if (knd == 1) {
                    oa[3 * w3i + 0] += cf * Ta[r] * sy1[r];
                    oa[3 * w3i + 1] += cf * Ta[r] * sy2[r];
                    oa[3 * w3i + 2] += cf * Ta[r] * sy3[r];
                } else {
                    oa[3 * w3i + 0] += cf * Ta[r];
                    oa[3 * w3i + 1] += cf * Tb[r];
                    oa[3 * w3i + 2] += cf * Tc[r];
                }
            }
        }
    }
    __syncthreads();

    // scatter: sum the 2 parity copies, one global atomic per (e,d)
    for (int idx = tid; idx < 32 * DOUT; idx += 256) {
        int e = idx / DOUT, d = idx % DOUT;
        float s = uni[e * 113 + d] + uni[3616 + e * 113 + d];
        unsafeAtomicAdd(&out_tp[ddn[e] * 112 + d], s);
    }
}

// ---------------------------------------------------------------------------
// knodestats: grid 320 x 512 (full-chip streaming).
// ---------------------------------------------------------------------------
__global__ void knodestats(const float* __restrict__ tp, const int* __restrict__ cnt,
                           const float* __restrict__ na, float* __restrict__ outb,
                           float* __restrict__ sbuf, int din, int dout)
{
    int t = threadIdx.x;
    if (t >= 448) return;
    int d = t % 112;
    int q = t / 112;
    if (d >= dout) return;
    float s = 0.f, s2 = 0.f;
    for (int n = blockIdx.x * 4 + q; n < N_NODES; n += 1280) {
        float c = fmaxf((float)cnt[n], 1.f);
        float v = tp[n * 112 + d] / c + (d < din ? na[n * 112 + d] : 0.f);
        outb[n * 112 + d] = v;
        s += v; s2 += v * v;
    }
    atomicAdd(&sbuf[d], s);
    atomicAdd(&sbuf[256 + d], s2);
}

// ---------------------------------------------------------------------------
// kapplyfuse: recompute scale/bias from sbuf per block, apply normalization,
// zero tp + the ENTIRE next sbuf (both halves).
// ---------------------------------------------------------------------------
__global__ void kapplyfuse(const float* __restrict__ outb, const float* __restrict__ sbuf,
                           float* __restrict__ dst, float* __restrict__ tpz,
                           float* __restrict__ nextsbuf, int dout, int vend)
{
    __shared__ float sc[112], bs[112];
    int tid = threadIdx.x;
    if (tid < dout) {
        const float invN = 1.f / (float)N_NODES;
        float scv, bsv;
        if (tid < 32 || tid >= vend) {
            float mn  = sbuf[tid] * invN;
            float var = sbuf[256 + tid] * invN - mn * mn;
            scv = rsqrtf(var + 1e-5f); bsv = mn;
        } else {
            int b = 32 + ((tid - 32) / 3) * 3;
            float n2 = (sbuf[256 + b] + sbuf[256 + b + 1] + sbuf[256 + b + 2]) * (invN / 3.f);
            scv = rsqrtf(n2 + 1e-5f); bsv = 0.f;
        }
        sc[tid] = scv; bs[tid] = bsv;
    }
    __syncthreads();
    int idx = blockIdx.x * 256 + tid;
    if (idx < N_NODES * dout) {
        int n = idx / dout, d = idx % dout;
        dst[n * 112 + d] = (outb[n * 112 + d] - bs[d]) * sc[d];
    }
    if (tpz) {
        for (int z = idx; z < N_NODES * 112; z += gridDim.x * 256) tpz[z] = 0.f;
        if (blockIdx.x == 0) { nextsbuf[tid] = 0.f; nextsbuf[256 + tid] = 0.f; }
    }
}

// ---------------------------------------------------------------------------
extern "C" void kernel_launch(void* const* d_in, const int* in_sizes, int n_in,
                              void* d_out, int out_size, void* d_ws, size_t ws_size,
                              hipStream_t stream)
{
    (void)in_sizes; (void)n_in; (void)out_size; (void)ws_size;
    const float* x     = (const float*)d_in[0];
    const float* pos   = (const float*)d_in[1];
    const float* sigma = (const float*)d_in[2];
    const float* eain  = (const float*)d_in[3];
    const float* nw1 = (const float*)d_in[4];  const float* nb1 = (const float*)d_in[5];
    const float* nw2 = (const float*)d_in[6];  const float* nb2 = (const float*)d_in[7];
    const float* ew1 = (const float*)d_in[8];  const float* eb1 = (const float*)d_in[9];
    const float* ew2 = (const float*)d_in[10]; const float* eb2 = (const float*)d_in[11];
    const float* fc1w = (const float*)d_in[12];
    const float* fc1b = (const float*)d_in[13];
    const float* fc2w[4] = {(const float*)d_in[14], (const float*)d_in[16],
                            (const float*)d_in[18], (const float*)d_in[20]};
    const float* fc2b[4] = {(const float*)d_in[15], (const float*)d_in[17],
                            (const float*)d_in[19], (const float*)d_in[21]};
    const int* ei = (const int*)d_in[22];

    float* ws   = (float*)d_ws;
    float* semb = ws + 0;            // N*32
    float* na   = ws + 320000;       // N*112
    float* outb = ws + 1440000;      // N*112
    float* tp   = ws + 2560000;      // N*112
    float* sh   = ws + 3680000;      // E*4
    float* eemb = ws + 3840000;      // E*32
    int*   cnt  = (int*)(ws + 5120000); // N
    float* sbufA = ws + 5130000;     // 512 (sums | sumsq)
    float* sbufB = ws + 5130512;     // 512
    unsigned short* wpk  = (unsigned short*)(ws + 5131264);  // fc2 packed: 798720 bf16
    unsigned short* w1pk = wpk + 798720;                      // fc1 packed: 36864 bf16
    float* out = (float*)d_out;

    const size_t WOFF_[4] = {0, 122880, 282624, 479232};

    hipMemsetAsync(cnt, 0, N_NODES * sizeof(int), stream);
    hipMemsetAsync(tp, 0, (size_t)N_NODES * 112 * sizeof(float), stream);
    hipMemsetAsync(sbufA, 0, 1024 * sizeof(float), stream);
    kpackf2<<<(99840 + 255) / 256, 256, 0, stream>>>(fc2w[0], fc2w[1], fc2w[2], fc2w[3], wpk);
    kpackf1<<<(4608 + 255) / 256, 256, 0, stream>>>(fc1w, w1pk);
    ksemb<<<(N_NODES + 255) / 256, 256, 0, stream>>>(sigma, semb);
    knodemlp<<<N_NODES / 8, 256, 0, stream>>>(x, semb, nw1, nb1, nw2, nb2, na);
    kedgepre<<<N_EDGES / 8, 256, 0, stream>>>(pos, eain, semb, ei, ew1, eb1, ew2, eb2,
                                              sh, eemb, cnt);

    const int DIN_[4]  = {32, 56, 80, 112};
    const int DOUT_[4] = {56, 80, 112, 112};
    const int VEND_[4] = {56, 80, 80, 80};
    for (int L = 0; L < 4; ++L) {
        float* sbuf  = (L & 1) ? sbufB : sbufA;
        float* nsbuf = (L & 1) ? sbufA : sbufB;
        switch (L) {
        case 0: ktp<0><<<N_EDGES / 32, 256, 0, stream>>>(na, eemb, sh, ei,
                    w1pk + 0 * 9216, fc1b + 0 * 96, wpk + WOFF_[0], fc2b[0], tp); break;
        case 1: ktp<1><<<N_EDGES / 32, 256, 0, stream>>>(na, eemb, sh, ei,
                    w1pk + 1 * 9216, fc1b + 1 * 96, wpk + WOFF_[1], fc2b[1], tp); break;
        case 2: ktp<2><<<N_EDGES / 32, 256, 0, stream>>>(na, eemb, sh, ei,
                    w1pk + 2 * 9216, fc1b + 2 * 96, wpk + WOFF_[2], fc2b[2], tp); break;
        default: ktp<3><<<N_EDGES / 32, 256, 0, stream>>>(na, eemb, sh, ei,
                    w1pk + 3 * 9216, fc1b + 3 * 96, wpk + WOFF_[3], fc2b[3], tp); break;
        }
        knodestats<<<320, 512, 0, stream>>>(tp, cnt, na, outb, sbuf, DIN_[L], DOUT_[L]);
        float* dstp = (L == 3) ? out : na;
        float* tpz  = (L == 3) ? nullptr : tp;
        kapplyfuse<<<(N_NODES * DOUT_[L] + 255) / 256, 256, 0, stream>>>(
            outb, sbuf, dstp, tpz, nsbuf, DOUT_[L], VEND_[L]);
    }
}

// Round 20
// 418.735 us; speedup vs baseline: 1.4178x; 1.1927x over previous
//
#include <hip/hip_runtime.h>
#include <math.h>

#define N_NODES 10000
#define N_EDGES 40000

typedef __attribute__((ext_vector_type(8))) short bf16x8;
typedef __attribute__((ext_vector_type(4))) float f32x4;

__device__ inline unsigned short f2bf(float f) {
    unsigned u = __float_as_uint(f);
    return (unsigned short)((u + 0x7FFFu + ((u >> 16) & 1u)) >> 16);
}

__device__ inline bf16x8 pack8(const float* p) {
    f32x4 a0 = *(const f32x4*)p;
    f32x4 a1 = *(const f32x4*)(p + 4);
    bf16x8 r;
    r[0] = (short)f2bf(a0.x); r[1] = (short)f2bf(a0.y);
    r[2] = (short)f2bf(a0.z); r[3] = (short)f2bf(a0.w);
    r[4] = (short)f2bf(a1.x); r[5] = (short)f2bf(a1.y);
    r[6] = (short)f2bf(a1.z); r[7] = (short)f2bf(a1.w);
    return r;
}

// ---------------------------------------------------------------------------
// Tensor-product path tables. kind: 0=(0,0,0) 1=(0,1,1) 2=(1,0,1) 3=(1,1,0) 4=(1,1,1)
// ---------------------------------------------------------------------------
template <int L> struct PC;
template <> struct PC<0> {
    static constexpr int NP = 2;
    static constexpr int woff[3]  = {0, 1024, 1280};
    static constexpr int l2m3[2]  = {5, 3};
    static constexpr int inoff[2] = {0, 0};
    static constexpr int outoff[2]= {0, 32};
    static constexpr int kind[2]  = {0, 1};
    static constexpr float coef[2]= {0.17677670f, 0.17677670f};
};
template <> struct PC<1> {
    static constexpr int NP = 5;
    static constexpr int woff[6]  = {0, 1024, 1280, 1344, 1600, 1664};
    static constexpr int l2m3[5]  = {5, 3, 3, 5, 3};
    static constexpr int inoff[5] = {0, 0, 32, 32, 32};
    static constexpr int outoff[5]= {0, 32, 32, 0, 56};
    static constexpr int kind[5]  = {0, 1, 2, 3, 4};
    static constexpr float coef[5]= {0.15811388f, 0.15811388f, 0.15811388f, 0.09128709f, 0.25f};
};
template <> struct PC<2> {
    static constexpr int NP = 8;
    static constexpr int woff[9]  = {0, 1024, 1280, 1344, 1600, 1664, 1728, 1792, 2048};
    static constexpr int l2m3[8]  = {5, 3, 3, 5, 3, 3, 3, 5};
    static constexpr int inoff[8] = {0, 0, 32, 32, 32, 56, 56, 56};
    static constexpr int outoff[8]= {0, 32, 32, 0, 56, 56, 32, 80};
    static constexpr int kind[8]  = {0, 1, 2, 3, 4, 2, 4, 3};
    static constexpr float coef[8]= {0.15811388f, 0.14433757f, 0.14433757f, 0.09128709f,
                                     0.17677670f, 0.25f, 0.10206207f, 0.20412415f};
};
template <> struct PC<3> {
    static constexpr int NP = 10;
    static constexpr int woff[11] = {0, 1024, 1280, 1344, 1600, 1664, 1728, 1792, 2048, 3072, 3328};
    static constexpr int l2m3[10] = {5, 3, 3, 5, 3, 3, 3, 5, 5, 3};
    static constexpr int inoff[10]= {0, 0, 32, 32, 32, 56, 56, 56, 80, 80};
    static constexpr int outoff[10]={0, 32, 32, 0, 56, 56, 32, 80, 80, 56};
    static constexpr int kind[10] = {0, 1, 2, 3, 4, 2, 4, 3, 0, 1};
    static constexpr float coef[10]={0.15811388f, 0.14433757f, 0.14433757f, 0.09128709f,
                                     0.10206207f, 0.14433757f, 0.10206207f, 0.09128709f,
                                     0.15811388f, 0.14433757f};
};

// ---------------------------------------------------------------------------
// kpackf2: all 4 fc2 weight matrices -> bf16 B-fragment layout (one launch).
// ---------------------------------------------------------------------------
__global__ void kpackf2(const float* __restrict__ w0c, const float* __restrict__ w1c,
                        const float* __restrict__ w2c, const float* __restrict__ w3c,
                        unsigned short* __restrict__ dst)
{
    int idx = blockIdx.x * 256 + threadIdx.x;
    if (idx >= 99840) return;
    const float* w; int ncol; size_t doff; int rel;
    if (idx < 15360)      { w = w0c; ncol = 1280; doff = 0;      rel = idx; }
    else if (idx < 35328) { w = w1c; ncol = 1664; doff = 122880; rel = idx - 15360; }
    else if (idx < 59904) { w = w2c; ncol = 2048; doff = 282624; rel = idx - 35328; }
    else                  { w = w3c; ncol = 3328; doff = 479232; rel = idx - 59904; }
    int lane = rel & 63;
    int rest = rel >> 6;
    int t  = rest % 3;
    int jt = rest / 3;
    int n  = jt * 16 + (lane & 15);
    int k0 = 32 * t + 8 * (lane >> 4);
    bf16x8 v;
#pragma unroll
    for (int i = 0; i < 8; ++i) v[i] = (short)f2bf(w[(size_t)(k0 + i) * ncol + n]);
    *(bf16x8*)(dst + doff + (size_t)rel * 8) = v;
}

// kpackf1: all 4 fc1 matrices (ncol=96) in one launch.
__global__ void kpackf1(const float* __restrict__ w, unsigned short* __restrict__ dst)
{
    int idx = blockIdx.x * 256 + threadIdx.x;
    if (idx >= 4 * 1152) return;
    int L = idx / 1152, rel = idx % 1152;
    int lane = rel & 63;
    int rest = rel >> 6;
    int t  = rest % 3;
    int jt = rest / 3;
    int n  = jt * 16 + (lane & 15);
    int k0 = 32 * t + 8 * (lane >> 4);
    const float* wl = w + (size_t)L * 9216;
    bf16x8 v;
#pragma unroll
    for (int i = 0; i < 8; ++i) v[i] = (short)f2bf(wl[(size_t)(k0 + i) * 96 + n]);
    *(bf16x8*)(dst + (size_t)L * 9216 + (size_t)rel * 8) = v;
}

// ---------------------------------------------------------------------------
__global__ void ksemb(const float* __restrict__ sigma, float* __restrict__ semb)
{
    int n = blockIdx.x * 256 + threadIdx.x;
    if (n >= N_NODES) return;
    float t = logf(sigma[n] * (1.0f / 0.031415926535897934f)) * 2171.4724095f;
#pragma unroll
    for (int j = 0; j < 16; ++j) {
        float f = expf(-0.61402269f * (float)j);
        float a = t * f;
        semb[n * 32 + j]      = sinf(a);
        semb[n * 32 + 16 + j] = cosf(a);
    }
}

// ---------------------------------------------------------------------------
__global__ void knodemlp(const float* __restrict__ x, const float* __restrict__ semb,
                         const float* __restrict__ w1, const float* __restrict__ b1,
                         const float* __restrict__ w2, const float* __restrict__ b2,
                         float* __restrict__ na)
{
    __shared__ float xin[8][106];
    __shared__ float h1[8][32];
    int tid = threadIdx.x;
    int n0  = blockIdx.x * 8;
    for (int idx = tid; idx < 8 * 106; idx += 256) {
        int e = idx / 106, q = idx % 106;
        int n = n0 + e;
        float v = 0.f;
        if (n < N_NODES) v = (q < 74) ? x[n * 74 + q] : semb[n * 32 + (q - 74)];
        xin[e][q] = v;
    }
    __syncthreads();
    {
        int e = tid / 32, c = tid % 32;
        float s = b1[c];
        for (int f = 0; f < 106; ++f) s += xin[e][f] * w1[f * 32 + c];
        h1[e][c] = fmaxf(s, 0.f);
    }
    __syncthreads();
    {
        int e = tid / 32, c = tid % 32;
        int n = n0 + e;
        if (n < N_NODES) {
            float s = b2[c];
#pragma unroll
            for (int f = 0; f < 32; ++f) s += h1[e][f] * w2[f * 32 + c];
            na[n * 112 + c] = s;
        }
    }
}

// ---------------------------------------------------------------------------
__global__ void kedgepre(const float* __restrict__ pos, const float* __restrict__ eattr_in,
                         const float* __restrict__ semb, const int* __restrict__ ei,
                         const float* __restrict__ w1, const float* __restrict__ b1,
                         const float* __restrict__ w2, const float* __restrict__ b2,
                         float* __restrict__ sh, float* __restrict__ eemb, int* __restrict__ cnt)
{
    __shared__ float ea[8][86];
    __shared__ float h1[8][32];
    __shared__ float dl[8];
    __shared__ int   sl[8];
    int tid = threadIdx.x;
    int e0  = blockIdx.x * 8;
    if (tid < 8) {
        int ge = e0 + tid;
        int s = ei[ge], d = ei[N_EDGES + ge];
        sl[tid] = s;
        float dx = pos[d * 3 + 0] - pos[s * 3 + 0];
        float dy = pos[d * 3 + 1] - pos[s * 3 + 1];
        float dz = pos[d * 3 + 2] - pos[s * 3 + 2];
        float dist = sqrtf(dx * dx + dy * dy + dz * dz);
        dist = fmaxf(dist, 1e-6f);
        dl[tid] = dist;
        float inv = 1.7320508f / dist;
        sh[ge * 4 + 0] = 1.f;
        sh[ge * 4 + 1] = dx * inv;
        sh[ge * 4 + 2] = dy * inv;
        sh[ge * 4 + 3] = dz * inv;
        atomicAdd(&cnt[d], 1);
    }
    __syncthreads();
    for (int idx = tid; idx < 8 * 86; idx += 256) {
        int e = idx / 86, q = idx % 86;
        int ge = e0 + e;
        float v;
        if (q < 4)       v = eattr_in[ge * 4 + q];
        else if (q < 36) v = semb[sl[e] * 32 + (q - 4)];
        else {
            int qq = q - 36;
            float off = 5.f * (float)qq / 49.f;
            float dd  = dl[e] - off;
            v = expf(-48.02f * dd * dd);
        }
        ea[e][q] = v;
    }
    __syncthreads();
    {
        int e = tid / 32, c = tid % 32;
        float s = b1[c];
        for (int f = 0; f < 86; ++f) s += ea[e][f] * w1[f * 32 + c];
        h1[e][c] = fmaxf(s, 0.f);
    }
    __syncthreads();
    {
        int e = tid / 32, c = tid % 32;
        float s = b2[c];
#pragma unroll
        for (int f = 0; f < 32; ++f) s += h1[e][f] * w2[f * 32 + c];
        eemb[(e0 + e) * 32 + c] = s;
    }
}

// ---------------------------------------------------------------------------
// K3 (R17-verbatim): fc1(MFMA) -> fc2(MFMA, 2-deep pipeline) -> TP epilogue,
// ZERO atomics. f32 xs; ys overlays uni copy-1. LDS ~44.2KB.
// ---------------------------------------------------------------------------
template <int L>
__global__ __launch_bounds__(256, 2) void ktp(
    const float* __restrict__ na, const float* __restrict__ eemb,
    const float* __restrict__ sh, const int* __restrict__ ei,
    const unsigned short* __restrict__ w1pk, const float* __restrict__ fc1b,
    const unsigned short* __restrict__ wpk, const float* __restrict__ fc2b,
    float* __restrict__ out_tp)
{
    using C = PC<L>;
    constexpr int DIN  = (L == 0 ? 32 : L == 1 ? 56 : L == 2 ? 80 : 112);
    constexpr int DOUT = (L == 0 ? 56 : L == 1 ? 80 : 112);

    alignas(16) __shared__ float uni[2 * 3616];
    alignas(16) __shared__ float xs[3616];
    __shared__ float shl4[128];
    __shared__ int   sdn[32], ddn[32];
    float* ys = &uni[3616];

    const int tid  = threadIdx.x;
    const int lane = tid & 63;
    const int wid  = tid >> 6;
    const int e0   = blockIdx.x * 32;
    const int m    = lane & 15;
    const int g    = lane >> 4;
    const int ehalf = wid >> 1;
    const int cpar  = wid & 1;

    if (tid < 32) { sdn[tid] = ei[e0 + tid]; ddn[tid] = ei[N_EDGES + e0 + tid]; }
    __syncthreads();

    for (int idx = tid; idx < 32 * DIN; idx += 256) {
        int e = idx / DIN, d = idx % DIN;
        xs[e * 113 + d] = na[sdn[e] * 112 + d];
    }
    for (int idx = tid; idx < 32 * 32; idx += 256) {
        int e = idx >> 5, d = idx & 31;
        ys[e * 36 + d] = na[ddn[e] * 112 + d];
    }
    if (tid < 128) shl4[tid] = sh[e0 * 4 + tid];
    __syncthreads();

    bf16x8 eaf[2][3];
#pragma unroll
    for (int mt = 0; mt < 2; ++mt) {
        int e = 16 * mt + m;
        eaf[mt][0] = pack8(&eemb[(size_t)(e0 + e) * 32 + 8 * g]);
        eaf[mt][1] = pack8(&xs[e * 113 + 8 * g]);
        eaf[mt][2] = pack8(&ys[e * 36 + 8 * g]);
    }

    const bf16x8* w1p = (const bf16x8*)w1pk;
#pragma unroll
    for (int pass = 0; pass < 2; ++pass) {
        int jt = wid + 4 * pass;
        if (jt < 6) {
            bf16x8 fb0 = w1p[(jt * 3 + 0) * 64 + lane];
            bf16x8 fb1 = w1p[(jt * 3 + 1) * 64 + lane];
            bf16x8 fb2 = w1p[(jt * 3 + 2) * 64 + lane];
            float bias = fc1b[jt * 16 + m];
            f32x4 a0 = {bias, bias, bias, bias};
            f32x4 a1 = a0;
            a0 = __builtin_amdgcn_mfma_f32_16x16x32_bf16(eaf[0][0], fb0, a0, 0, 0, 0);
            a1 = __builtin_amdgcn_mfma_f32_16x16x32_bf16(eaf[1][0], fb0, a1, 0, 0, 0);
            a0 = __builtin_amdgcn_mfma_f32_16x16x32_bf16(eaf[0][1], fb1, a0, 0, 0, 0);
            a1 = __builtin_amdgcn_mfma_f32_16x16x32_bf16(eaf[1][1], fb1, a1, 0, 0, 0);
            a0 = __builtin_amdgcn_mfma_f32_16x16x32_bf16(eaf[0][2], fb2, a0, 0, 0, 0);
            a1 = __builtin_amdgcn_mfma_f32_16x16x32_bf16(eaf[1][2], fb2, a1, 0, 0, 0);
#pragma unroll
            for (int r = 0; r < 4; ++r) {
                uni[(0  + 4 * g + r) * 100 + jt * 16 + m] = fmaxf(a0[r], 0.f);
                uni[(16 + 4 * g + r) * 100 + jt * 16 + m] = fmaxf(a1[r], 0.f);
            }
        }
    }
    __syncthreads();

    bf16x8 afrag[3];
#pragma unroll
    for (int t = 0; t < 3; ++t)
        afrag[t] = pack8(&uni[(16 * ehalf + m) * 100 + 32 * t + 8 * g]);

    float sy1[4], sy2[4], sy3[4];
#pragma unroll
    for (int r = 0; r < 4; ++r) {
        int e = 16 * ehalf + 4 * g + r;
        sy1[r] = shl4[e * 4 + 1];
        sy2[r] = shl4[e * 4 + 2];
        sy3[r] = shl4[e * 4 + 3];
    }
    __syncthreads();
    for (int idx = tid; idx < 2 * 3616; idx += 256) uni[idx] = 0.f;   // oacc2 := 0
    __syncthreads();

    const bf16x8* wp = (const bf16x8*)wpk;
    const int ebase = 16 * ehalf + 4 * g;
    const int lj    = m;
    float* oaccw = &uni[cpar * 3616];

#pragma clang loop unroll(disable)
    for (int p = 0; p < C::NP; ++p) {
        const int w0    = C::woff[p];
        const int iters = (C::woff[p + 1] - w0) / 32;   // tiles per parity (even, >=2)
        const int jtb   = w0 / 16 + cpar;
        const int sh3   = C::l2m3[p];
        const int mask  = (1 << sh3) - 1;
        const int w3i   = (16 * cpar + lj) & mask;
        const float cf  = C::coef[p];
        const int IN = C::inoff[p], OUT = C::outoff[p];
        const int knd = C::kind[p];

        float Ta[4], Tb[4], Tc[4];
#pragma unroll
        for (int s = 0; s < 4; ++s) { Ta[s] = 0.f; Tb[s] = 0.f; Tc[s] = 0.f; }

        auto epi = [&](f32x4 acc, int i2) {
            const int u = (i2 * 16 + lj) >> sh3;
            if (knd <= 1) {
#pragma unroll
                for (int r = 0; r < 4; ++r)
                    Ta[r] += xs[(ebase + r) * 113 + IN + u] * acc[r];
            } else if (knd == 2) {
#pragma unroll
                for (int r = 0; r < 4; ++r) {
                    const float* xe = &xs[(ebase + r) * 113 + IN + 3 * u];
                    Ta[r] += xe[0] * acc[r];
                    Tb[r] += xe[1] * acc[r];
                    Tc[r] += xe[2] * acc[r];
                }
            } else if (knd == 3) {
#pragma unroll
                for (int r = 0; r < 4; ++r) {
                    const float* xe = &xs[(ebase + r) * 113 + IN + 3 * u];
                    Ta[r] += (xe[0] * sy1[r] + xe[1] * sy2[r] + xe[2] * sy3[r]) * acc[r];
                }
            } else {
#pragma unroll
                for (int r = 0; r < 4; ++r) {
                    const float* xe = &xs[(ebase + r) * 113 + IN + 3 * u];
                    Ta[r] += (xe[1] * sy3[r] - xe[2] * sy2[r]) * acc[r];
                    Tb[r] += (xe[2] * sy1[r] - xe[0] * sy3[r]) * acc[r];
                    Tc[r] += (xe[0] * sy2[r] - xe[1] * sy1[r]) * acc[r];
                }
            }
        };

        // 2-deep software pipeline: stages A (even i) and B (odd i).
        int jtA = jtb;
        bf16x8 A0 = wp[(jtA * 3 + 0) * 64 + lane];
        bf16x8 A1 = wp[(jtA * 3 + 1) * 64 + lane];
        bf16x8 A2 = wp[(jtA * 3 + 2) * 64 + lane];
        float  Ab = fc2b[jtA * 16 + lj];
        int jtB = jtb + 2;
        bf16x8 B0 = wp[(jtB * 3 + 0) * 64 + lane];
        bf16x8 B1 = wp[(jtB * 3 + 1) * 64 + lane];
        bf16x8 B2 = wp[(jtB * 3 + 2) * 64 + lane];
        float  Bb = fc2b[jtB * 16 + lj];

#pragma clang loop unroll(disable)
        for (int i = 0; i < iters; i += 2) {
            f32x4 accA = {Ab, Ab, Ab, Ab};
            accA = __builtin_amdgcn_mfma_f32_16x16x32_bf16(afrag[0], A0, accA, 0, 0, 0);
            accA = __builtin_amdgcn_mfma_f32_16x16x32_bf16(afrag[1], A1, accA, 0, 0, 0);
            accA = __builtin_amdgcn_mfma_f32_16x16x32_bf16(afrag[2], A2, accA, 0, 0, 0);
            if (i + 2 < iters) {
                int jtn = jtb + 2 * (i + 2);
                A0 = wp[(jtn * 3 + 0) * 64 + lane];
                A1 = wp[(jtn * 3 + 1) * 64 + lane];
                A2 = wp[(jtn * 3 + 2) * 64 + lane];
                Ab = fc2b[jtn * 16 + lj];
            }
            epi(accA, 2 * i + cpar);

            f32x4 accB = {Bb, Bb, Bb, Bb};
            accB = __builtin_amdgcn_mfma_f32_16x16x32_bf16(afrag[0], B0, accB, 0, 0, 0);
            accB = __builtin_amdgcn_mfma_f32_16x16x32_bf16(afrag[1], B1, accB, 0, 0, 0);
            accB = __builtin_amdgcn_mfma_f32_16x16x32_bf16(afrag[2], B2, accB, 0, 0, 0);
            if (i + 3 < iters) {
                int jtn = jtb + 2 * (i + 3);
                B0 = wp[(jtn * 3 + 0) * 64 + lane];
                B1 = wp[(jtn * 3 + 1) * 64 + lane];
                B2 = wp[(jtn * 3 + 2) * 64 + lane];
                Bb = fc2b[jtn * 16 + lj];
            }
            epi(accB, 2 * (i + 1) + cpar);
        }

        // within-wave alias (lj, lj+8) for mask==7 paths -> shfl combine
        const bool halfred = (mask == 7);
        if (halfred) {
#pragma unroll
            for (int s = 0; s < 4; ++s) {
                Ta[s] += __shfl_xor(Ta[s], 8);
                if (knd == 2 || knd == 4) {
                    Tb[s] += __shfl_xor(Tb[s], 8);
                    Tc[s] += __shfl_xor(Tc[s], 8);
                }
            }
        }
        if (!halfred || (lj & 8) == 0) {
#pragma unroll
            for (int r = 0; r < 4; ++r) {
                const int e = ebase + r;
                float* oa = &oaccw[e * 113 + OUT];
                if (knd == 0 || knd == 3) {
                    oa[w3i] += cf * Ta[r];
                } else if (knd == 1) {
                    oa[3 * w3i + 0] += cf * Ta[r] * sy1[r];
                    oa[3 * w3i + 1] += cf * Ta[r] * sy2[r];
                    oa[3 * w3i + 2] += cf * Ta[r] * sy3[r];
                } else {
                    oa[3 * w3i + 0] += cf * Ta[r];
                    oa[3 * w3i + 1] += cf * Tb[r];
                    oa[3 * w3i + 2] += cf * Tc[r];
                }
            }
        }
    }
    __syncthreads();

    // scatter: sum the 2 parity copies, one global atomic per (e,d)
    for (int idx = tid; idx < 32 * DOUT; idx += 256) {
        int e = idx / DOUT, d = idx % DOUT;
        float s = uni[e * 113 + d] + uni[3616 + e * 113 + d];
        unsafeAtomicAdd(&out_tp[ddn[e] * 112 + d], s);
    }
}

// ---------------------------------------------------------------------------
// knodestats: grid 128 x 512, IN-BLOCK 4-way reduction before the atomic:
// 1 atomic per (d, block) => 128 collisions/address (was 1280 at grid 320).
// ---------------------------------------------------------------------------
__global__ void knodestats(const float* __restrict__ tp, const int* __restrict__ cnt,
                           const float* __restrict__ na, float* __restrict__ outb,
                           float* __restrict__ sbuf, int din, int dout)
{
    __shared__ float r1[448], r2[448];
    int t = threadIdx.x;
    int d = t % 112;
    int q = t / 112;
    float s = 0.f, s2 = 0.f;
    if (t < 448 && d < dout) {
        for (int n = blockIdx.x * 4 + q; n < N_NODES; n += 512) {
            float c = fmaxf((float)cnt[n], 1.f);
            float v = tp[n * 112 + d] / c + (d < din ? na[n * 112 + d] : 0.f);
            outb[n * 112 + d] = v;
            s += v; s2 += v * v;
        }
    }
    if (t < 448) { r1[t] = s; r2[t] = s2; }
    __syncthreads();
    if (t < 112 && t < dout) {
        float ss  = r1[t] + r1[t + 112] + r1[t + 224] + r1[t + 336];
        float ss2 = r2[t] + r2[t + 112] + r2[t + 224] + r2[t + 336];
        atomicAdd(&sbuf[t], ss);
        atomicAdd(&sbuf[256 + t], ss2);
    }
}

// ---------------------------------------------------------------------------
// kapplyfuse: recompute scale/bias from sbuf per block, apply normalization,
// zero tp + the ENTIRE next sbuf (both halves).
// ---------------------------------------------------------------------------
__global__ void kapplyfuse(const float* __restrict__ outb, const float* __restrict__ sbuf,
                           float* __restrict__ dst, float* __restrict__ tpz,
                           float* __restrict__ nextsbuf, int dout, int vend)
{
    __shared__ float sc[112], bs[112];
    int tid = threadIdx.x;
    if (tid < dout) {
        const float invN = 1.f / (float)N_NODES;
        float scv, bsv;
        if (tid < 32 || tid >= vend) {
            float mn  = sbuf[tid] * invN;
            float var = sbuf[256 + tid] * invN - mn * mn;
            scv = rsqrtf(var + 1e-5f); bsv = mn;
        } else {
            int b = 32 + ((tid - 32) / 3) * 3;
            float n2 = (sbuf[256 + b] + sbuf[256 + b + 1] + sbuf[256 + b + 2]) * (invN / 3.f);
            scv = rsqrtf(n2 + 1e-5f); bsv = 0.f;
        }
        sc[tid] = scv; bs[tid] = bsv;
    }
    __syncthreads();
    int idx = blockIdx.x * 256 + tid;
    if (idx < N_NODES * dout) {
        int n = idx / dout, d = idx % dout;
        dst[n * 112 + d] = (outb[n * 112 + d] - bs[d]) * sc[d];
    }
    if (tpz) {
        for (int z = idx; z < N_NODES * 112; z += gridDim.x * 256) tpz[z] = 0.f;
        if (blockIdx.x == 0) { nextsbuf[tid] = 0.f; nextsbuf[256 + tid] = 0.f; }
    }
}

// ---------------------------------------------------------------------------
extern "C" void kernel_launch(void* const* d_in, const int* in_sizes, int n_in,
                              void* d_out, int out_size, void* d_ws, size_t ws_size,
                              hipStream_t stream)
{
    (void)in_sizes; (void)n_in; (void)out_size; (void)ws_size;
    const float* x     = (const float*)d_in[0];
    const float* pos   = (const float*)d_in[1];
    const float* sigma = (const float*)d_in[2];
    const float* eain  = (const float*)d_in[3];
    const float* nw1 = (const float*)d_in[4];  const float* nb1 = (const float*)d_in[5];
    const float* nw2 = (const float*)d_in[6];  const float* nb2 = (const float*)d_in[7];
    const float* ew1 = (const float*)d_in[8];  const float* eb1 = (const float*)d_in[9];
    const float* ew2 = (const float*)d_in[10]; const float* eb2 = (const float*)d_in[11];
    const float* fc1w = (const float*)d_in[12];
    const float* fc1b = (const float*)d_in[13];
    const float* fc2w[4] = {(const float*)d_in[14], (const float*)d_in[16],
                            (const float*)d_in[18], (const float*)d_in[20]};
    const float* fc2b[4] = {(const float*)d_in[15], (const float*)d_in[17],
                            (const float*)d_in[19], (const float*)d_in[21]};
    const int* ei = (const int*)d_in[22];

    float* ws   = (float*)d_ws;
    float* semb = ws + 0;            // N*32
    float* na   = ws + 320000;       // N*112
    float* outb = ws + 1440000;      // N*112
    float* tp   = ws + 2560000;      // N*112
    float* sh   = ws + 3680000;      // E*4
    float* eemb = ws + 3840000;      // E*32
    int*   cnt  = (int*)(ws + 5120000); // N
    float* sbufA = ws + 5130000;     // 512 (sums | sumsq)
    float* sbufB = ws + 5130512;     // 512
    unsigned short* wpk  = (unsigned short*)(ws + 5131264);  // fc2 packed: 798720 bf16
    unsigned short* w1pk = wpk + 798720;                      // fc1 packed: 36864 bf16
    float* out = (float*)d_out;

    const size_t WOFF_[4] = {0, 122880, 282624, 479232};

    hipMemsetAsync(cnt, 0, N_NODES * sizeof(int), stream);
    hipMemsetAsync(tp, 0, (size_t)N_NODES * 112 * sizeof(float), stream);
    hipMemsetAsync(sbufA, 0, 1024 * sizeof(float), stream);
    kpackf2<<<(99840 + 255) / 256, 256, 0, stream>>>(fc2w[0], fc2w[1], fc2w[2], fc2w[3], wpk);
    kpackf1<<<(4608 + 255) / 256, 256, 0, stream>>>(fc1w, w1pk);
    ksemb<<<(N_NODES + 255) / 256, 256, 0, stream>>>(sigma, semb);
    knodemlp<<<N_NODES / 8, 256, 0, stream>>>(x, semb, nw1, nb1, nw2, nb2, na);
    kedgepre<<<N_EDGES / 8, 256, 0, stream>>>(pos, eain, semb, ei, ew1, eb1, ew2, eb2,
                                              sh, eemb, cnt);

    const int DIN_[4]  = {32, 56, 80, 112};
    const int DOUT_[4] = {56, 80, 112, 112};
    const int VEND_[4] = {56, 80, 80, 80};
    for (int L = 0; L < 4; ++L) {
        float* sbuf  = (L & 1) ? sbufB : sbufA;
        float* nsbuf = (L & 1) ? sbufA : sbufB;
        switch (L) {
        case 0: ktp<0><<<N_EDGES / 32, 256, 0, stream>>>(na, eemb, sh, ei,
                    w1pk + 0 * 9216, fc1b + 0 * 96, wpk + WOFF_[0], fc2b[0], tp); break;
        case 1: ktp<1><<<N_EDGES / 32, 256, 0, stream>>>(na, eemb, sh, ei,
                    w1pk + 1 * 9216, fc1b + 1 * 96, wpk + WOFF_[1], fc2b[1], tp); break;
        case 2: ktp<2><<<N_EDGES / 32, 256, 0, stream>>>(na, eemb, sh, ei,
                    w1pk + 2 * 9216, fc1b + 2 * 96, wpk + WOFF_[2], fc2b[2], tp); break;
        default: ktp<3><<<N_EDGES / 32, 256, 0, stream>>>(na, eemb, sh, ei,
                    w1pk + 3 * 9216, fc1b + 3 * 96, wpk + WOFF_[3], fc2b[3], tp); break;
        }
        knodestats<<<128, 512, 0, stream>>>(tp, cnt, na, outb, sbuf, DIN_[L], DOUT_[L]);
        float* dstp = (L == 3) ? out : na;
        float* tpz  = (L == 3) ? nullptr : tp;
        kapplyfuse<<<(N_NODES * DOUT_[L] + 255) / 256, 256, 0, stream>>>(
            outb, sbuf, dstp, tpz, nsbuf, DOUT_[L], VEND_[L]);
    }
}